// Round 4
// baseline (209.139 us; speedup 1.0000x reference)
//
#include <hip/hip_runtime.h>

#define N_ROWS  4096
#define IN_DIM  256
#define OUT_DIM 256

// base kernel (A): out = x@w1 + b1 + sb*eps_b
#define RA 4          // rows per block
#define TA 256        // threads

// eps kernel (B): out += sum_i x * sw * eps_w   (double-buffered sw tiles)
#define RB 8          // rows per block (one per wave)
#define TB 512        // threads
#define TI 32         // i-tile
#define NTILES (IN_DIM / TI)

typedef float f32x4 __attribute__((ext_vector_type(4)));

__device__ __forceinline__ float4 nt_load4(const float4* p) {
    f32x4 v = __builtin_nontemporal_load((const f32x4*)p);
    return make_float4(v.x, v.y, v.z, v.w);
}

// ---------------------------------------------------------------------------
// Kernel 0: precompute exp(log_sigma) into workspace.
// ---------------------------------------------------------------------------
__global__ void bayes_exp_kernel(const float* __restrict__ logw,
                                 const float* __restrict__ logb,
                                 float* __restrict__ sw,
                                 float* __restrict__ sb) {
    int idx = blockIdx.x * blockDim.x + threadIdx.x;
    if (idx < IN_DIM * OUT_DIM) sw[idx] = __expf(logw[idx]);
    if (idx < OUT_DIM)          sb[idx] = __expf(logb[idx]);
}

// ---------------------------------------------------------------------------
// Kernel A: base[n,o] = b1[o] + sb[o]*eps_b[n,o] + sum_i x[n,i]*w1[i,o]
// w1 (256 KB) is L2-resident (no concurrent streaming kernel) — read direct.
// ---------------------------------------------------------------------------
template <bool PRE>
__global__ __launch_bounds__(TA) void bayes_base_kernel(
    const float* __restrict__ x,      // [N, IN]
    const float* __restrict__ eps_b,  // [N, OUT]
    const float* __restrict__ w1,     // [IN, OUT]
    const float* __restrict__ b1,     // [OUT]
    const float* __restrict__ sbl,    // [OUT] exp(logb2) or logb2
    float* __restrict__ out)          // [N, OUT]
{
    __shared__ float xs[RA * IN_DIM];
    const int tid = threadIdx.x;
    const int n0  = blockIdx.x * RA;

    ((float4*)xs)[tid] = ((const float4*)(x + (size_t)n0 * IN_DIM))[tid];
    __syncthreads();

    const int row = tid >> 6;
    const int o4  = tid & 63;
    const int n   = n0 + row;

    const float4* w4 = (const float4*)w1 + o4;
    float4 acc = make_float4(0.f, 0.f, 0.f, 0.f);

    #pragma unroll 4
    for (int i = 0; i < IN_DIM; ++i) {
        const float  xv = xs[row * IN_DIM + i];
        const float4 w  = w4[i * (OUT_DIM / 4)];
        acc.x = fmaf(xv, w.x, acc.x);
        acc.y = fmaf(xv, w.y, acc.y);
        acc.z = fmaf(xv, w.z, acc.z);
        acc.w = fmaf(xv, w.w, acc.w);
    }

    const float4 eb = nt_load4((const float4*)(eps_b + (size_t)n * OUT_DIM) + o4);
    const float4 b  = ((const float4*)b1)[o4];
    float4 sb       = ((const float4*)sbl)[o4];
    if (!PRE) {
        sb.x = __expf(sb.x); sb.y = __expf(sb.y);
        sb.z = __expf(sb.z); sb.w = __expf(sb.w);
    }

    float4 res;
    res.x = acc.x + fmaf(sb.x, eb.x, b.x);
    res.y = acc.y + fmaf(sb.y, eb.y, b.y);
    res.z = acc.z + fmaf(sb.z, eb.z, b.z);
    res.w = acc.w + fmaf(sb.w, eb.w, b.w);

    ((float4*)(out + (size_t)n * OUT_DIM))[o4] = res;
}

// ---------------------------------------------------------------------------
// Kernel B: out[n,o] += sum_i x[n,i] * sw[i,o] * eps_w[n,i,o]
// sw staged in double-buffered LDS tiles: ONE barrier per tile; the stage of
// tile t+1 is issued right after the barrier and its latency hides under the
// 32-iteration compute of tile t. eps_w is a pure nontemporal float4 stream.
// ---------------------------------------------------------------------------
template <bool PRE>
__global__ __launch_bounds__(TB) void bayes_eps_kernel(
    const float* __restrict__ x,      // [N, IN]
    const float* __restrict__ eps_w,  // [N, IN, OUT]
    const float* __restrict__ swl,    // [IN, OUT] exp(logw2) or logw2
    float* __restrict__ out)          // [N, OUT] (holds base from kernel A)
{
    __shared__ float xs[RB * IN_DIM];        // 8 KB
    __shared__ float st[2 * TI * OUT_DIM];   // 64 KB -> 72 KB total, 2 blocks/CU

    const int tid = threadIdx.x;
    const int n0  = blockIdx.x * RB;

    // Stage x rows (RB*IN_DIM = 2048 floats = 512 float4s).
    ((float4*)xs)[tid] = ((const float4*)(x + (size_t)n0 * IN_DIM))[tid];

    const int row = tid >> 6;
    const int o4  = tid & 63;
    const int n   = n0 + row;

    const float4* e4base = (const float4*)(eps_w + (size_t)n * IN_DIM * OUT_DIM) + o4;

    // Base value written by kernel A (sequential on stream -> visible).
    const float4 base = ((const float4*)(out + (size_t)n * OUT_DIM))[o4];

    // ---- staging helper: tile t -> buffer half b ----
    #define STAGE(t, b)                                                        \
        do {                                                                   \
            const float4* _src = (const float4*)(swl + (t) * TI * OUT_DIM);    \
            float4 _v[4];                                                      \
            _Pragma("unroll")                                                  \
            for (int _k = 0; _k < 4; ++_k) _v[_k] = _src[tid + _k * TB];       \
            if (!PRE) {                                                        \
                _Pragma("unroll")                                              \
                for (int _k = 0; _k < 4; ++_k) {                               \
                    _v[_k].x = __expf(_v[_k].x); _v[_k].y = __expf(_v[_k].y);  \
                    _v[_k].z = __expf(_v[_k].z); _v[_k].w = __expf(_v[_k].w);  \
                }                                                              \
            }                                                                  \
            float4* _dst = (float4*)(st + (b) * TI * OUT_DIM);                 \
            _Pragma("unroll")                                                  \
            for (int _k = 0; _k < 4; ++_k) _dst[tid + _k * TB] = _v[_k];       \
        } while (0)

    STAGE(0, 0);

    float4 acc = make_float4(0.f, 0.f, 0.f, 0.f);
    int cur = 0;

    for (int t = 0; t < NTILES; ++t) {
        // buf[cur] staged & everyone done reading buf[cur^1] from tile t-1
        __syncthreads();
        if (t + 1 < NTILES) STAGE(t + 1, cur ^ 1);

        const float4* e4 = e4base + (size_t)t * TI * (OUT_DIM / 4);
        const float4* sp = (const float4*)(st + cur * TI * OUT_DIM);

        #pragma unroll 4
        for (int i = 0; i < TI; ++i) {
            const float  xv = xs[row * IN_DIM + t * TI + i];  // wave-uniform
            const float4 s  = sp[i * 64 + o4];
            const float4 e  = nt_load4(e4 + i * 64);
            acc.x = fmaf(xv * s.x, e.x, acc.x);
            acc.y = fmaf(xv * s.y, e.y, acc.y);
            acc.z = fmaf(xv * s.z, e.z, acc.z);
            acc.w = fmaf(xv * s.w, e.w, acc.w);
        }
        cur ^= 1;
    }
    #undef STAGE

    float4 res;
    res.x = base.x + acc.x;
    res.y = base.y + acc.y;
    res.z = base.z + acc.z;
    res.w = base.w + acc.w;
    ((float4*)(out + (size_t)n * OUT_DIM))[o4] = res;
}

extern "C" void kernel_launch(void* const* d_in, const int* in_sizes, int n_in,
                              void* d_out, int out_size, void* d_ws, size_t ws_size,
                              hipStream_t stream) {
    const float* x     = (const float*)d_in[0];
    const float* eps_w = (const float*)d_in[1];
    const float* eps_b = (const float*)d_in[2];
    const float* w1    = (const float*)d_in[3];
    const float* logw2 = (const float*)d_in[4];
    const float* b1    = (const float*)d_in[5];
    const float* logb2 = (const float*)d_in[6];
    float* out = (float*)d_out;

    const size_t need = (size_t)(IN_DIM * OUT_DIM + OUT_DIM) * sizeof(float);

    if (ws_size >= need) {
        float* sw = (float*)d_ws;
        float* sb = sw + IN_DIM * OUT_DIM;
        bayes_exp_kernel<<<(IN_DIM * OUT_DIM + 255) / 256, 256, 0, stream>>>(
            logw2, logb2, sw, sb);
        bayes_base_kernel<true><<<N_ROWS / RA, TA, 0, stream>>>(
            x, eps_b, w1, b1, sb, out);
        bayes_eps_kernel<true><<<N_ROWS / RB, TB, 0, stream>>>(
            x, eps_w, sw, out);
    } else {
        bayes_base_kernel<false><<<N_ROWS / RA, TA, 0, stream>>>(
            x, eps_b, w1, b1, logb2, out);
        bayes_eps_kernel<false><<<N_ROWS / RB, TB, 0, stream>>>(
            x, eps_w, logw2, out);
    }
}